// Round 3
// baseline (113.868 us; speedup 1.0000x reference)
//
#include <hip/hip_runtime.h>

#define H 1024
#define W 1024
#define OH 1016
#define OW 1016
#define NB 16

#define OTW 64         // output tile cols
#define OTH 32         // output tile rows
#define ITH 40         // input tile rows  (OTH + 8)
#define DTH 36         // dev/prod tile rows (OTH + 4)

#define W4I 18         // input f4 per row (72 cols)
#define W4D 17         // dev/prod f4 per row (68 cols)
#define W4O 16         // output f4 per row (64 cols)
#define S4  19         // padded row stride in float4

__device__ __forceinline__ void add4(float4& a, const float4& b) {
    a.x += b.x; a.y += b.y; a.z += b.z; a.w += b.w;
}

__global__ __launch_bounds__(256)
void cov_kernel(const float* __restrict__ x,
                const float* __restrict__ y,
                float* __restrict__ out) {
    __shared__ float4 sx4[ITH][S4];   // raw x tile
    __shared__ float4 sy4[ITH][S4];   // raw y tile
    __shared__ float4 pr4[DTH][S4];   // dev-product tile

    const int b  = blockIdx.z;
    const int i0 = blockIdx.y * OTH;
    const int j0 = blockIdx.x * OTW;
    const int tid = threadIdx.x;
    const float inv25 = 1.0f / 25.0f;

    const float* xb = x + (size_t)b * H * W;
    const float* yb = y + (size_t)b * H * W;

    // ---- Phase 1: global -> LDS (40 rows x 18 float4) ----
    for (int idx = tid; idx < ITH * W4I; idx += 256) {
        int r  = idx / W4I;
        int c4 = idx - r * W4I;
        int gr = i0 + r;
        int gc = j0 + c4 * 4;
        float4 vx = make_float4(0.f, 0.f, 0.f, 0.f);
        float4 vy = vx;
        if (gr < H && gc <= W - 4) {
            vx = *reinterpret_cast<const float4*>(xb + gr * W + gc);
            vy = *reinterpret_cast<const float4*>(yb + gr * W + gc);
        }
        sx4[r][c4] = vx;
        sy4[r][c4] = vy;
    }
    __syncthreads();

    // ---- Phase 2: vertical 5-sum (regs) + horizontal 5-sum + dev product ----
    for (int idx = tid; idx < DTH * W4D; idx += 256) {
        int r  = idx / W4D;
        int c4 = idx - r * W4D;
        float4 ax0 = make_float4(0.f, 0.f, 0.f, 0.f), ax1 = ax0;
        float4 ay0 = ax0, ay1 = ax0;
        float4 cx0, cx1, cy0, cy1;               // center row r+2
        #pragma unroll
        for (int u = 0; u < 5; ++u) {
            float4 t0 = sx4[r + u][c4];
            float4 t1 = sx4[r + u][c4 + 1];
            float4 s0 = sy4[r + u][c4];
            float4 s1 = sy4[r + u][c4 + 1];
            add4(ax0, t0); add4(ax1, t1);
            add4(ay0, s0); add4(ay1, s1);
            if (u == 2) { cx0 = t0; cx1 = t1; cy0 = s0; cy1 = s1; }
        }
        float sx0 = ax0.x + ax0.y + ax0.z + ax0.w + ax1.x;
        float sx1 = sx0 - ax0.x + ax1.y;
        float sx2 = sx1 - ax0.y + ax1.z;
        float sx3 = sx2 - ax0.z + ax1.w;
        float sy0 = ay0.x + ay0.y + ay0.z + ay0.w + ay1.x;
        float sy1 = sy0 - ay0.x + ay1.y;
        float sy2 = sy1 - ay0.y + ay1.z;
        float sy3 = sy2 - ay0.z + ay1.w;
        float4 p;
        p.x = (cx0.z - sx0 * inv25) * (cy0.z - sy0 * inv25);
        p.y = (cx0.w - sx1 * inv25) * (cy0.w - sy1 * inv25);
        p.z = (cx1.x - sx2 * inv25) * (cy1.x - sy2 * inv25);
        p.w = (cx1.y - sx3 * inv25) * (cy1.y - sy3 * inv25);
        pr4[r][c4] = p;
    }
    __syncthreads();

    // ---- Phase 3: vertical 5-sum of products (regs) + horizontal 5-sum + store ----
    for (int idx = tid; idx < OTH * W4O; idx += 256) {
        int r  = idx / W4O;
        int c4 = idx - r * W4O;
        int gi = i0 + r;
        int gj = j0 + c4 * 4;
        if (gi < OH && gj <= OW - 4) {
            float4 A = make_float4(0.f, 0.f, 0.f, 0.f), B = A;
            #pragma unroll
            for (int u = 0; u < 5; ++u) {
                add4(A, pr4[r + u][c4]);
                add4(B, pr4[r + u][c4 + 1]);
            }
            float s0 = A.x + A.y + A.z + A.w + B.x;
            float s1 = s0 - A.x + B.y;
            float s2 = s1 - A.y + B.z;
            float s3 = s2 - A.z + B.w;
            float4 o;
            o.x = s0 * inv25; o.y = s1 * inv25; o.z = s2 * inv25; o.w = s3 * inv25;
            *reinterpret_cast<float4*>(out + (size_t)b * OH * OW + (size_t)gi * OW + gj) = o;
        }
    }
}

extern "C" void kernel_launch(void* const* d_in, const int* in_sizes, int n_in,
                              void* d_out, int out_size, void* d_ws, size_t ws_size,
                              hipStream_t stream) {
    const float* x = (const float*)d_in[0];
    const float* y = (const float*)d_in[1];
    float* out = (float*)d_out;

    dim3 grid((OW + OTW - 1) / OTW, (OH + OTH - 1) / OTH, NB);
    dim3 block(256);
    cov_kernel<<<grid, block, 0, stream>>>(x, y, out);
}

// Round 4
// 52.637 us; speedup vs baseline: 2.1633x; 2.1633x over previous
//
#include <hip/hip_runtime.h>

#define H 1024
#define W 1024
#define OH 1016
#define OW 1016
#define NB 16
#define BAND 16            // output rows per block
#define STEPS (BAND + 8)   // input rows swept per block
#define WCOLS 248          // useful output cols per 64-lane wave
#define NWX 5              // ceil(1016 / 248)

__global__ __launch_bounds__(64)
void cov_kernel(const float* __restrict__ xg,
                const float* __restrict__ yg,
                float* __restrict__ outg) {
    const int t    = threadIdx.x;      // lane 0..63
    const int wx   = blockIdx.x;       // column group
    const int band = blockIdx.y;       // row band
    const int img  = blockIdx.z;

    const int cb = wx * WCOLS + 4 * t;         // this lane's first column
    const int O  = band * BAND;                // first output row of band
    const bool lok = (cb <= W - 4);            // load guard (cols)
    const bool sok = (t <= 61) && (cb <= OW - 4);  // store guard

    const float* xb = xg + (size_t)img * H * W;
    const float* yb = yg + (size_t)img * H * W;
    float* ob = outg + (size_t)img * OH * OW;

    const float4 z4 = make_float4(0.f, 0.f, 0.f, 0.f);
    float4 hx[5], hy[5], hp[5];        // 5-row histories (statically indexed)
    #pragma unroll
    for (int i = 0; i < 5; ++i) { hx[i] = z4; hy[i] = z4; hp[i] = z4; }
    float4 csx = z4, csy = z4, ps = z4;  // vertical rolling 5-sums
    const float k = 1.0f / 25.0f;

    #pragma unroll
    for (int s = 0; s < STEPS; ++s) {
        const int r = O + s;                    // input row
        float4 nx = z4, ny = z4;
        if (lok && r < H) {
            nx = *reinterpret_cast<const float4*>(xb + (size_t)r * W + cb);
            ny = *reinterpret_cast<const float4*>(yb + (size_t)r * W + cb);
        }
        const int ph = s % 5;                   // history slot (constant after unroll)
        csx.x += nx.x - hx[ph].x; csx.y += nx.y - hx[ph].y;
        csx.z += nx.z - hx[ph].z; csx.w += nx.w - hx[ph].w;
        csy.x += ny.x - hy[ph].x; csy.y += ny.y - hy[ph].y;
        csy.z += ny.z - hy[ph].z; csy.w += ny.w - hy[ph].w;
        hx[ph] = nx; hy[ph] = ny;

        if (s >= 4) {                            // prod row p = r-4 ready
            const int pc = (ph + 3) % 5;         // slot holding input row r-2 (center)
            // neighbor lane's colsums (cols cb+4..cb+7)
            float bx0 = __shfl_down(csx.x, 1), bx1 = __shfl_down(csx.y, 1);
            float bx2 = __shfl_down(csx.z, 1), bx3 = __shfl_down(csx.w, 1);
            float by0 = __shfl_down(csy.x, 1), by1 = __shfl_down(csy.y, 1);
            float by2 = __shfl_down(csy.z, 1), by3 = __shfl_down(csy.w, 1);
            // neighbor lane's center values (cols cb+4, cb+5)
            float cx2 = __shfl_down(hx[pc].x, 1), cx3 = __shfl_down(hx[pc].y, 1);
            float cy2 = __shfl_down(hy[pc].x, 1), cy3 = __shfl_down(hy[pc].y, 1);

            // horizontal 5-window sums of vertical colsums (rolling)
            float sx0 = csx.x + csx.y + csx.z + csx.w + bx0;
            float sx1 = sx0 - csx.x + bx1;
            float sx2 = sx1 - csx.y + bx2;
            float sx3 = sx2 - csx.z + bx3;
            float sy0 = csy.x + csy.y + csy.z + csy.w + by0;
            float sy1 = sy0 - csy.x + by1;
            float sy2 = sy1 - csy.y + by2;
            float sy3 = sy2 - csy.z + by3;

            // dev product at prod row r-4, cols cb..cb+3 (centers x[r-2][cb+2..cb+5])
            float4 p;
            p.x = (hx[pc].z - sx0 * k) * (hy[pc].z - sy0 * k);
            p.y = (hx[pc].w - sx1 * k) * (hy[pc].w - sy1 * k);
            p.z = (cx2      - sx2 * k) * (cy2      - sy2 * k);
            p.w = (cx3      - sx3 * k) * (cy3      - sy3 * k);

            const int pp = (s + 1) % 5;          // (s-4)%5: prod history slot
            ps.x += p.x - hp[pp].x; ps.y += p.y - hp[pp].y;
            ps.z += p.z - hp[pp].z; ps.w += p.w - hp[pp].w;
            hp[pp] = p;

            if (s >= 8) {                        // out row o = r-8 ready
                float bp0 = __shfl_down(ps.x, 1), bp1 = __shfl_down(ps.y, 1);
                float bp2 = __shfl_down(ps.z, 1), bp3 = __shfl_down(ps.w, 1);
                float s0 = ps.x + ps.y + ps.z + ps.w + bp0;
                float s1 = s0 - ps.x + bp1;
                float s2 = s1 - ps.y + bp2;
                float s3 = s2 - ps.z + bp3;
                const int o = O + s - 8;
                if (sok && o < OH) {
                    float4 ov = make_float4(s0 * k, s1 * k, s2 * k, s3 * k);
                    *reinterpret_cast<float4*>(ob + (size_t)o * OW + cb) = ov;
                }
            }
        }
    }
}

extern "C" void kernel_launch(void* const* d_in, const int* in_sizes, int n_in,
                              void* d_out, int out_size, void* d_ws, size_t ws_size,
                              hipStream_t stream) {
    const float* x = (const float*)d_in[0];
    const float* y = (const float*)d_in[1];
    float* out = (float*)d_out;

    dim3 grid(NWX, (OH + BAND - 1) / BAND, NB);   // 5 x 64 x 16 = 5120 one-wave blocks
    dim3 block(64);
    cov_kernel<<<grid, block, 0, stream>>>(x, y, out);
}

// Round 6
// 48.671 us; speedup vs baseline: 2.3396x; 1.0815x over previous
//
#include <hip/hip_runtime.h>

#define H 1024
#define W 1024
#define OH 1016
#define OW 1016
#define NB 16
#define BAND 16            // output rows per wave
#define STEPS (BAND + 8)   // input rows swept per wave
#define WCOLS 248          // useful output cols per 64-lane wave
#define NWX 5              // ceil(1016 / 248)
#define WPB 4              // waves per block

typedef float vfloat4 __attribute__((ext_vector_type(4)));

__global__ __launch_bounds__(256)
void cov_kernel(const float* __restrict__ xg,
                const float* __restrict__ yg,
                float* __restrict__ outg) {
    const int t    = threadIdx.x & 63;             // lane 0..63
    const int wv   = threadIdx.x >> 6;             // wave in block
    const int wx   = blockIdx.x;                   // column group
    const int band = blockIdx.y * WPB + wv;        // row band
    const int img  = blockIdx.z;

    const int cb = wx * WCOLS + 4 * t;             // lane's first column
    const int O  = band * BAND;                    // first output row of band
    const bool lok = (cb <= W - 4);
    const bool sok = (t <= 61) && (cb <= OW - 4);

    const float* xb = xg + (size_t)img * H * W;
    const float* yb = yg + (size_t)img * H * W;
    float* ob = outg + (size_t)img * OH * OW;

    const float4 z4 = make_float4(0.f, 0.f, 0.f, 0.f);
    float4 hx[5], hy[5], hp[5];
    #pragma unroll
    for (int i = 0; i < 5; ++i) { hx[i] = z4; hy[i] = z4; hp[i] = z4; }
    float4 csx = z4, csy = z4, ps = z4;
    const float k = 1.0f / 25.0f;

    // depth-2 prefetch pipeline (pending rows s+1, s+2; statically indexed)
    float4 pnx[2], pny[2];
    #pragma unroll
    for (int i = 0; i < 2; ++i) {
        const int r = O + i;
        float4 vx = z4, vy = z4;
        if (lok && r < H) {
            vx = *reinterpret_cast<const float4*>(xb + (size_t)r * W + cb);
            vy = *reinterpret_cast<const float4*>(yb + (size_t)r * W + cb);
        }
        pnx[i] = vx; pny[i] = vy;
    }

    #pragma unroll
    for (int s = 0; s < STEPS; ++s) {
        const float4 nx = pnx[s & 1];
        const float4 ny = pny[s & 1];
        if (s + 2 < STEPS) {                        // issue load for row s+2
            const int r = O + s + 2;
            float4 vx = z4, vy = z4;
            if (lok && r < H) {
                vx = *reinterpret_cast<const float4*>(xb + (size_t)r * W + cb);
                vy = *reinterpret_cast<const float4*>(yb + (size_t)r * W + cb);
            }
            pnx[s & 1] = vx; pny[s & 1] = vy;
        }

        const int ph = s % 5;
        csx.x += nx.x - hx[ph].x; csx.y += nx.y - hx[ph].y;
        csx.z += nx.z - hx[ph].z; csx.w += nx.w - hx[ph].w;
        csy.x += ny.x - hy[ph].x; csy.y += ny.y - hy[ph].y;
        csy.z += ny.z - hy[ph].z; csy.w += ny.w - hy[ph].w;
        hx[ph] = nx; hy[ph] = ny;

        if (s >= 4) {
            const int pc = (ph + 3) % 5;            // slot of center row r-2
            float bx0 = __shfl_down(csx.x, 1), bx1 = __shfl_down(csx.y, 1);
            float bx2 = __shfl_down(csx.z, 1), bx3 = __shfl_down(csx.w, 1);
            float by0 = __shfl_down(csy.x, 1), by1 = __shfl_down(csy.y, 1);
            float by2 = __shfl_down(csy.z, 1), by3 = __shfl_down(csy.w, 1);
            float cx2 = __shfl_down(hx[pc].x, 1), cx3 = __shfl_down(hx[pc].y, 1);
            float cy2 = __shfl_down(hy[pc].x, 1), cy3 = __shfl_down(hy[pc].y, 1);

            float sx0 = csx.x + csx.y + csx.z + csx.w + bx0;
            float sx1 = sx0 - csx.x + bx1;
            float sx2 = sx1 - csx.y + bx2;
            float sx3 = sx2 - csx.z + bx3;
            float sy0 = csy.x + csy.y + csy.z + csy.w + by0;
            float sy1 = sy0 - csy.x + by1;
            float sy2 = sy1 - csy.y + by2;
            float sy3 = sy2 - csy.z + by3;

            float4 p;
            p.x = (hx[pc].z - sx0 * k) * (hy[pc].z - sy0 * k);
            p.y = (hx[pc].w - sx1 * k) * (hy[pc].w - sy1 * k);
            p.z = (cx2      - sx2 * k) * (cy2      - sy2 * k);
            p.w = (cx3      - sx3 * k) * (cy3      - sy3 * k);

            const int pp = (s + 1) % 5;
            ps.x += p.x - hp[pp].x; ps.y += p.y - hp[pp].y;
            ps.z += p.z - hp[pp].z; ps.w += p.w - hp[pp].w;
            hp[pp] = p;

            if (s >= 8) {
                float bp0 = __shfl_down(ps.x, 1), bp1 = __shfl_down(ps.y, 1);
                float bp2 = __shfl_down(ps.z, 1), bp3 = __shfl_down(ps.w, 1);
                float s0 = ps.x + ps.y + ps.z + ps.w + bp0;
                float s1 = s0 - ps.x + bp1;
                float s2 = s1 - ps.y + bp2;
                float s3 = s2 - ps.z + bp3;
                const int o = O + s - 8;
                if (sok && o < OH) {
                    vfloat4 ov = { s0 * k, s1 * k, s2 * k, s3 * k };
                    __builtin_nontemporal_store(ov,
                        reinterpret_cast<vfloat4*>(ob + (size_t)o * OW + cb));
                }
            }
        }
    }
}

extern "C" void kernel_launch(void* const* d_in, const int* in_sizes, int n_in,
                              void* d_out, int out_size, void* d_ws, size_t ws_size,
                              hipStream_t stream) {
    const float* x = (const float*)d_in[0];
    const float* y = (const float*)d_in[1];
    float* out = (float*)d_out;

    // 64 bands total, 4 per block
    dim3 grid(NWX, 64 / WPB, NB);   // 5 x 16 x 16 = 1280 blocks of 4 waves
    dim3 block(256);
    cov_kernel<<<grid, block, 0, stream>>>(x, y, out);
}